// Round 1
// baseline (573.212 us; speedup 1.0000x reference)
//
#include <hip/hip_runtime.h>
#include <math.h>

// Problem constants (reference: BATCH=2048, D=256, TEMP=0.5)
#define NB      2048
#define TWO_N   4096
#define DIM     256
#define INV_T   2.0f          // 1/TEMP
#define EPS     1e-12f

// ---------------------------------------------------------------------------
// K1: L2-normalize rows of [emb_i; emb_j] into z (4096 x 256 f32 in ws).
// One wave (64 lanes) per row, float4 per lane. Also zeroes den[] and out[0].
// ---------------------------------------------------------------------------
__global__ __launch_bounds__(256) void nrm_kernel(
    const float* __restrict__ emb_i, const float* __restrict__ emb_j,
    float* __restrict__ z, float* __restrict__ den, float* __restrict__ out)
{
    int t = threadIdx.x;
    int wave = t >> 6, lane = t & 63;
    int r = blockIdx.x * 4 + wave;              // 0..4095
    const float* src = (r < NB) ? (emb_i + (size_t)r * DIM)
                                : (emb_j + (size_t)(r - NB) * DIM);
    float4 v = ((const float4*)src)[lane];      // d = lane*4 .. lane*4+3
    float s = v.x*v.x + v.y*v.y + v.z*v.z + v.w*v.w;
    #pragma unroll
    for (int off = 32; off >= 1; off >>= 1)
        s += __shfl_xor(s, off, 64);
    float scale = 1.0f / fmaxf(sqrtf(s), EPS);
    float4 o; o.x = v.x*scale; o.y = v.y*scale; o.z = v.z*scale; o.w = v.w*scale;
    ((float4*)(z + (size_t)r * DIM))[lane] = o;

    if (t < 4) den[blockIdx.x * 4 + t] = 0.0f;  // ws is poisoned each call
    if (blockIdx.x == 0 && t == 0) out[0] = 0.0f;
}

// ---------------------------------------------------------------------------
// K2: for each row r accumulate den[r] = sum_{j != r} exp(2 * z_r . z_j).
// Grid: (64 r-tiles, 16 j-splits). Block: 256 threads.
// A-tile: 64 rows x 256 f32 in LDS (64 KB), column-XOR-swizzled so the
// 4-distinct-row broadcast reads land on 2 banks max (2-way = free).
// Thread tile: 4 m-rows x 16 j-cols (4 j per iter x 4 iters).
// ---------------------------------------------------------------------------
__global__ __launch_bounds__(256) void simexp_kernel(
    const float* __restrict__ z, float* __restrict__ den)
{
    __shared__ float A[64 * 256];               // exactly 64 KB
    int t = threadIdx.x;
    int rbase = blockIdx.x * 64;
    int jbase = blockIdx.y * 256;

    // Stage A tile (coalesced float4), swizzle: col4' = col4 ^ (row & 15)
    for (int idx = t; idx < 64 * 64; idx += 256) {
        int row = idx >> 6, c4 = idx & 63;
        float4 v = ((const float4*)(z + (size_t)(rbase + row) * DIM))[c4];
        ((float4*)(A + row * 256))[c4 ^ (row & 15)] = v;
    }
    __syncthreads();

    int tx = t & 15, ty = t >> 4;               // tx: j-group, ty: m-group
    int m0 = ty * 4;
    int r0 = rbase + m0;
    const float4* A0 = (const float4*)(A + (m0 + 0) * 256);
    const float4* A1 = (const float4*)(A + (m0 + 1) * 256);
    const float4* A2 = (const float4*)(A + (m0 + 2) * 256);
    const float4* A3 = (const float4*)(A + (m0 + 3) * 256);
    int x0 = (m0 + 0) & 15, x1 = (m0 + 1) & 15, x2 = (m0 + 2) & 15, x3 = (m0 + 3) & 15;

    float den0 = 0.f, den1 = 0.f, den2 = 0.f, den3 = 0.f;

    for (int iter = 0; iter < 4; ++iter) {
        int j0 = jbase + iter * 64 + tx * 4;
        const float4* B0 = (const float4*)(z + (size_t)(j0 + 0) * DIM);
        const float4* B1 = (const float4*)(z + (size_t)(j0 + 1) * DIM);
        const float4* B2 = (const float4*)(z + (size_t)(j0 + 2) * DIM);
        const float4* B3 = (const float4*)(z + (size_t)(j0 + 3) * DIM);

        float d[4][4];
        #pragma unroll
        for (int i = 0; i < 4; ++i)
            #pragma unroll
            for (int jj = 0; jj < 4; ++jj) d[i][jj] = 0.f;

        #pragma unroll 4
        for (int c = 0; c < 64; ++c) {
            float4 b0 = B0[c], b1 = B1[c], b2 = B2[c], b3 = B3[c];
            float4 a0 = A0[c ^ x0];
            float4 a1 = A1[c ^ x1];
            float4 a2 = A2[c ^ x2];
            float4 a3 = A3[c ^ x3];
            d[0][0] += a0.x*b0.x + a0.y*b0.y + a0.z*b0.z + a0.w*b0.w;
            d[0][1] += a0.x*b1.x + a0.y*b1.y + a0.z*b1.z + a0.w*b1.w;
            d[0][2] += a0.x*b2.x + a0.y*b2.y + a0.z*b2.z + a0.w*b2.w;
            d[0][3] += a0.x*b3.x + a0.y*b3.y + a0.z*b3.z + a0.w*b3.w;
            d[1][0] += a1.x*b0.x + a1.y*b0.y + a1.z*b0.z + a1.w*b0.w;
            d[1][1] += a1.x*b1.x + a1.y*b1.y + a1.z*b1.z + a1.w*b1.w;
            d[1][2] += a1.x*b2.x + a1.y*b2.y + a1.z*b2.z + a1.w*b2.w;
            d[1][3] += a1.x*b3.x + a1.y*b3.y + a1.z*b3.z + a1.w*b3.w;
            d[2][0] += a2.x*b0.x + a2.y*b0.y + a2.z*b0.z + a2.w*b0.w;
            d[2][1] += a2.x*b1.x + a2.y*b1.y + a2.z*b1.z + a2.w*b1.w;
            d[2][2] += a2.x*b2.x + a2.y*b2.y + a2.z*b2.z + a2.w*b2.w;
            d[2][3] += a2.x*b3.x + a2.y*b3.y + a2.z*b3.z + a2.w*b3.w;
            d[3][0] += a3.x*b0.x + a3.y*b0.y + a3.z*b0.z + a3.w*b0.w;
            d[3][1] += a3.x*b1.x + a3.y*b1.y + a3.z*b1.z + a3.w*b1.w;
            d[3][2] += a3.x*b2.x + a3.y*b2.y + a3.z*b2.z + a3.w*b2.w;
            d[3][3] += a3.x*b3.x + a3.y*b3.y + a3.z*b3.z + a3.w*b3.w;
        }

        #pragma unroll
        for (int jj = 0; jj < 4; ++jj) {
            int j = j0 + jj;
            float e0 = __expf(INV_T * d[0][jj]);
            float e1 = __expf(INV_T * d[1][jj]);
            float e2 = __expf(INV_T * d[2][jj]);
            float e3 = __expf(INV_T * d[3][jj]);
            if (j != r0 + 0) den0 += e0;
            if (j != r0 + 1) den1 += e1;
            if (j != r0 + 2) den2 += e2;
            if (j != r0 + 3) den3 += e3;
        }
    }

    // Reduce across the 16 tx-lanes sharing the same m-rows (contiguous lanes)
    #pragma unroll
    for (int off = 8; off >= 1; off >>= 1) {
        den0 += __shfl_down(den0, off, 16);
        den1 += __shfl_down(den1, off, 16);
        den2 += __shfl_down(den2, off, 16);
        den3 += __shfl_down(den3, off, 16);
    }
    if (tx == 0) {
        atomicAdd(&den[r0 + 0], den0);
        atomicAdd(&den[r0 + 1], den1);
        atomicAdd(&den[r0 + 2], den2);
        atomicAdd(&den[r0 + 3], den3);
    }
}

// ---------------------------------------------------------------------------
// K3: loss_r = log(den[r]) - 2 * (z_r . z_partner); out = sum / 4096.
// One wave per row.
// ---------------------------------------------------------------------------
__global__ __launch_bounds__(256) void loss_kernel(
    const float* __restrict__ z, const float* __restrict__ den,
    float* __restrict__ out)
{
    int t = threadIdx.x;
    int wave = t >> 6, lane = t & 63;
    int r = blockIdx.x * 4 + wave;
    int partner = (r < NB) ? r + NB : r - NB;
    float4 a = ((const float4*)(z + (size_t)r * DIM))[lane];
    float4 b = ((const float4*)(z + (size_t)partner * DIM))[lane];
    float s = a.x*b.x + a.y*b.y + a.z*b.z + a.w*b.w;
    #pragma unroll
    for (int off = 32; off >= 1; off >>= 1)
        s += __shfl_xor(s, off, 64);
    if (lane == 0) {
        float val = logf(den[r]) - INV_T * s;
        atomicAdd(out, val * (1.0f / (float)TWO_N));
    }
}

// ---------------------------------------------------------------------------
extern "C" void kernel_launch(void* const* d_in, const int* in_sizes, int n_in,
                              void* d_out, int out_size, void* d_ws, size_t ws_size,
                              hipStream_t stream)
{
    const float* emb_i = (const float*)d_in[0];
    const float* emb_j = (const float*)d_in[1];
    float* out = (float*)d_out;

    float* z   = (float*)d_ws;                    // 4096*256 f32 = 4 MB
    float* den = z + (size_t)TWO_N * DIM;         // 4096 f32

    nrm_kernel<<<TWO_N / 4, 256, 0, stream>>>(emb_i, emb_j, z, den, out);

    dim3 g2(TWO_N / 64, TWO_N / 256);             // 64 r-tiles x 16 j-splits
    simexp_kernel<<<g2, 256, 0, stream>>>(z, den);

    loss_kernel<<<TWO_N / 4, 256, 0, stream>>>(z, den, out);
}

// Round 2
// 121.676 us; speedup vs baseline: 4.7110x; 4.7110x over previous
//
#include <hip/hip_runtime.h>
#include <hip/hip_bf16.h>
#include <math.h>

// Problem constants (reference: BATCH=2048, D=256, TEMP=0.5)
#define NB      2048
#define TWO_N   4096
#define DIM     256
#define EPS     1e-12f

typedef __attribute__((ext_vector_type(8))) short  bf16x8;   // 8 bf16 = 4 VGPRs
typedef __attribute__((ext_vector_type(4))) float  f32x4;    // MFMA C/D

// ---------------------------------------------------------------------------
// K1: L2-normalize rows of [emb_i; emb_j] -> bf16 z (4096 x 256).
// One wave per row. Also zeroes den[] and out[0].
// ---------------------------------------------------------------------------
__global__ __launch_bounds__(256) void nrm_kernel(
    const float* __restrict__ emb_i, const float* __restrict__ emb_j,
    __hip_bfloat16* __restrict__ zb, float* __restrict__ den,
    float* __restrict__ out)
{
    int t = threadIdx.x;
    int wave = t >> 6, lane = t & 63;
    int r = blockIdx.x * 4 + wave;              // 0..4095
    const float* src = (r < NB) ? (emb_i + (size_t)r * DIM)
                                : (emb_j + (size_t)(r - NB) * DIM);
    float4 v = ((const float4*)src)[lane];      // d = lane*4 .. lane*4+3
    float s = v.x*v.x + v.y*v.y + v.z*v.z + v.w*v.w;
    #pragma unroll
    for (int off = 32; off >= 1; off >>= 1)
        s += __shfl_xor(s, off, 64);
    float scale = 1.0f / fmaxf(sqrtf(s), EPS);
    union { __hip_bfloat16 h[4]; uint2 u; } pk;
    pk.h[0] = __float2bfloat16(v.x * scale);
    pk.h[1] = __float2bfloat16(v.y * scale);
    pk.h[2] = __float2bfloat16(v.z * scale);
    pk.h[3] = __float2bfloat16(v.w * scale);
    ((uint2*)(zb + (size_t)r * DIM))[lane] = pk.u;

    if (t < 4) den[blockIdx.x * 4 + t] = 0.0f;  // ws is poisoned each call
    if (blockIdx.x == 0 && t == 0) out[0] = 0.0f;
}

// ---------------------------------------------------------------------------
// K2: den[r] += sum_{j != r, j in col-tile} exp(2 * z_r . z_j), via bf16 MFMA.
// Grid 32x32 blocks, 256 threads = 4 waves in 2x2; block tile 128x128,
// wave tile 64x64 (4x4 MFMA 16x16x32 accumulators), K = 256 = 8 steps.
// No LDS: A/B fragments are 16B contiguous row chunks of z, read from L2
// (z = 2 MB, resident in every XCD's 4 MiB L2).
// Fragment layouts (verified m89/m91): A[m=lane&15][k=quad*8+j],
// B[k=quad*8+j][n=lane&15], C/D: col=lane&15, row=quad*4+reg.
// ---------------------------------------------------------------------------
__global__ __launch_bounds__(256) void simexp_kernel(
    const __hip_bfloat16* __restrict__ zb, float* __restrict__ den)
{
    const short* Z = (const short*)zb;
    int t = threadIdx.x;
    int w = t >> 6, lane = t & 63;
    int quad = lane >> 4, c16 = lane & 15;
    int wm = w >> 1, wn = w & 1;
    int rbase = blockIdx.x * 128 + wm * 64;
    int jbase = blockIdx.y * 128 + wn * 64;

    // Per-lane fragment base pointers (k-offset quad*8; kk adds 32*k shorts)
    const short* ap[4];
    const short* bp[4];
    #pragma unroll
    for (int mt = 0; mt < 4; ++mt)
        ap[mt] = Z + (size_t)(rbase + mt * 16 + c16) * DIM + quad * 8;
    #pragma unroll
    for (int nt = 0; nt < 4; ++nt)
        bp[nt] = Z + (size_t)(jbase + nt * 16 + c16) * DIM + quad * 8;

    f32x4 acc[4][4];
    #pragma unroll
    for (int mt = 0; mt < 4; ++mt)
        #pragma unroll
        for (int nt = 0; nt < 4; ++nt)
            acc[mt][nt] = (f32x4){0.f, 0.f, 0.f, 0.f};

    #pragma unroll
    for (int kk = 0; kk < 8; ++kk) {
        bf16x8 af[4], bfr[4];
        #pragma unroll
        for (int mt = 0; mt < 4; ++mt)
            af[mt] = *(const bf16x8*)(ap[mt] + kk * 32);
        #pragma unroll
        for (int nt = 0; nt < 4; ++nt)
            bfr[nt] = *(const bf16x8*)(bp[nt] + kk * 32);
        #pragma unroll
        for (int mt = 0; mt < 4; ++mt)
            #pragma unroll
            for (int nt = 0; nt < 4; ++nt)
                acc[mt][nt] = __builtin_amdgcn_mfma_f32_16x16x32_bf16(
                    af[mt], bfr[nt], acc[mt][nt], 0, 0, 0);
    }

    // Epilogue: e = exp(2*sim), mask diagonal, per-row partial sums.
    // Row of acc[mt][*][rg] = rbase + mt*16 + quad*4 + rg; col = jbase+nt*16+c16
    float rsum[4][4];                            // [mt][rg]
    #pragma unroll
    for (int mt = 0; mt < 4; ++mt)
        #pragma unroll
        for (int rg = 0; rg < 4; ++rg)
            rsum[mt][rg] = 0.f;

    #pragma unroll
    for (int mt = 0; mt < 4; ++mt) {
        #pragma unroll
        for (int nt = 0; nt < 4; ++nt) {
            int j = jbase + nt * 16 + c16;
            #pragma unroll
            for (int rg = 0; rg < 4; ++rg) {
                int r = rbase + mt * 16 + quad * 4 + rg;
                float e = __expf(2.0f * acc[mt][nt][rg]);
                rsum[mt][rg] += (r == j) ? 0.f : e;
            }
        }
    }

    // Reduce across the 16 lanes of each quad (they hold different cols of
    // the same rows), then one atomic per row from lane c16==0.
    #pragma unroll
    for (int mt = 0; mt < 4; ++mt) {
        #pragma unroll
        for (int rg = 0; rg < 4; ++rg) {
            float v = rsum[mt][rg];
            v += __shfl_xor(v, 1, 64);
            v += __shfl_xor(v, 2, 64);
            v += __shfl_xor(v, 4, 64);
            v += __shfl_xor(v, 8, 64);
            if (c16 == 0)
                atomicAdd(&den[rbase + mt * 16 + quad * 4 + rg], v);
        }
    }
}

// ---------------------------------------------------------------------------
// K3: positives recomputed in fp32 from raw inputs. One wave per pair r:
// handles rows r and r+NB (both share the same positive dot).
// loss contribution = log(den[r]) + log(den[r+NB]) - 4 * (z_r . z_{r+NB}).
// ---------------------------------------------------------------------------
__global__ __launch_bounds__(256) void loss_kernel(
    const float* __restrict__ emb_i, const float* __restrict__ emb_j,
    const float* __restrict__ den, float* __restrict__ out)
{
    int t = threadIdx.x;
    int wave = t >> 6, lane = t & 63;
    int r = blockIdx.x * 4 + wave;              // pair index 0..2047
    float4 a = ((const float4*)(emb_i + (size_t)r * DIM))[lane];
    float4 b = ((const float4*)(emb_j + (size_t)r * DIM))[lane];
    float sa = a.x*a.x + a.y*a.y + a.z*a.z + a.w*a.w;
    float sb = b.x*b.x + b.y*b.y + b.z*b.z + b.w*b.w;
    float sd = a.x*b.x + a.y*b.y + a.z*b.z + a.w*b.w;
    #pragma unroll
    for (int off = 32; off >= 1; off >>= 1) {
        sa += __shfl_xor(sa, off, 64);
        sb += __shfl_xor(sb, off, 64);
        sd += __shfl_xor(sd, off, 64);
    }
    if (lane == 0) {
        float ni = fmaxf(sqrtf(sa), EPS);
        float nj = fmaxf(sqrtf(sb), EPS);
        float s = sd / (ni * nj);
        float val = logf(den[r]) + logf(den[r + NB]) - 4.0f * s;
        atomicAdd(out, val * (1.0f / (float)TWO_N));
    }
}

// ---------------------------------------------------------------------------
extern "C" void kernel_launch(void* const* d_in, const int* in_sizes, int n_in,
                              void* d_out, int out_size, void* d_ws, size_t ws_size,
                              hipStream_t stream)
{
    const float* emb_i = (const float*)d_in[0];
    const float* emb_j = (const float*)d_in[1];
    float* out = (float*)d_out;

    __hip_bfloat16* zb = (__hip_bfloat16*)d_ws;           // 4096*256 bf16 = 2 MB
    float* den = (float*)((char*)d_ws + (size_t)TWO_N * DIM * sizeof(__hip_bfloat16));

    nrm_kernel<<<TWO_N / 4, 256, 0, stream>>>(emb_i, emb_j, zb, den, out);

    dim3 g2(TWO_N / 128, TWO_N / 128);                    // 32 x 32
    simexp_kernel<<<g2, 256, 0, stream>>>(zb, den);

    loss_kernel<<<NB / 4, 256, 0, stream>>>(emb_i, emb_j, den, out);
}

// Round 3
// 101.542 us; speedup vs baseline: 5.6451x; 1.1983x over previous
//
#include <hip/hip_runtime.h>
#include <hip/hip_bf16.h>
#include <math.h>

// Problem constants (reference: BATCH=2048, D=256, TEMP=0.5)
#define NB      2048
#define TWO_N   4096
#define DIM     256
#define EPS     1e-12f

typedef __attribute__((ext_vector_type(8))) short  bf16x8;   // 8 bf16 = 4 VGPRs
typedef __attribute__((ext_vector_type(4))) float  f32x4;    // MFMA C/D

// ---------------------------------------------------------------------------
// K1: one wave per PAIR r in [0,2048): L2-normalize emb_i[r] -> z[r] and
// emb_j[r] -> z[r+NB] (bf16), and write the fp32-exact positive dot
// pos[r] = <z_i, z_j>. Also zeroes den[4096].
// ---------------------------------------------------------------------------
__global__ __launch_bounds__(256) void nrm_kernel(
    const float* __restrict__ emb_i, const float* __restrict__ emb_j,
    __hip_bfloat16* __restrict__ zb, float* __restrict__ pos,
    float* __restrict__ den)
{
    int t = threadIdx.x;
    int wave = t >> 6, lane = t & 63;
    int r = blockIdx.x * 4 + wave;              // pair index 0..2047
    float4 a = ((const float4*)(emb_i + (size_t)r * DIM))[lane];
    float4 b = ((const float4*)(emb_j + (size_t)r * DIM))[lane];
    float sa = a.x*a.x + a.y*a.y + a.z*a.z + a.w*a.w;
    float sb = b.x*b.x + b.y*b.y + b.z*b.z + b.w*b.w;
    float sd = a.x*b.x + a.y*b.y + a.z*b.z + a.w*b.w;
    #pragma unroll
    for (int off = 32; off >= 1; off >>= 1) {
        sa += __shfl_xor(sa, off, 64);
        sb += __shfl_xor(sb, off, 64);
        sd += __shfl_xor(sd, off, 64);
    }
    float si = 1.0f / fmaxf(sqrtf(sa), EPS);
    float sj = 1.0f / fmaxf(sqrtf(sb), EPS);

    union { __hip_bfloat16 h[4]; uint2 u; } pk;
    pk.h[0] = __float2bfloat16(a.x * si);
    pk.h[1] = __float2bfloat16(a.y * si);
    pk.h[2] = __float2bfloat16(a.z * si);
    pk.h[3] = __float2bfloat16(a.w * si);
    ((uint2*)(zb + (size_t)r * DIM))[lane] = pk.u;
    pk.h[0] = __float2bfloat16(b.x * sj);
    pk.h[1] = __float2bfloat16(b.y * sj);
    pk.h[2] = __float2bfloat16(b.z * sj);
    pk.h[3] = __float2bfloat16(b.w * sj);
    ((uint2*)(zb + (size_t)(r + NB) * DIM))[lane] = pk.u;

    if (lane == 0) pos[r] = sd * si * sj;
    if (t < 8) den[blockIdx.x * 8 + t] = 0.0f;  // 512 blocks x 8 = 4096
}

// ---------------------------------------------------------------------------
// K2: den[r] += sum_j exp(2 * z_r . z_j) via bf16 MFMA, symmetric:
// only blocks with bx <= by do work; off-diagonal blocks scatter both
// row-sums (into den[row-tile]) and col-sums (into den[col-tile]).
// Block tile 128x128, 4 waves in 2x2, wave tile 64x64 = 4x4 MFMA 16x16x32.
// K-loop register double-buffered (fragments straight from L2; no LDS).
// Fragment layouts (verified m89/m91): A[m=lane&15][k=quad*8+j],
// B[k=quad*8+j][n=lane&15], C/D: col=lane&15, row=quad*4+reg.
// ---------------------------------------------------------------------------
__global__ __launch_bounds__(256, 2) void simexp_kernel(
    const __hip_bfloat16* __restrict__ zb, float* __restrict__ den)
{
    int bx = blockIdx.x, by = blockIdx.y;
    if (bx > by) return;                        // symmetry: upper triangle only

    const short* Z = (const short*)zb;
    int t = threadIdx.x;
    int w = t >> 6, lane = t & 63;
    int quad = lane >> 4, c16 = lane & 15;
    int wm = w >> 1, wn = w & 1;
    int rbase = bx * 128 + wm * 64;
    int jbase = by * 128 + wn * 64;

    const short* ap[4];
    const short* bp[4];
    #pragma unroll
    for (int mt = 0; mt < 4; ++mt)
        ap[mt] = Z + (size_t)(rbase + mt * 16 + c16) * DIM + quad * 8;
    #pragma unroll
    for (int nt = 0; nt < 4; ++nt)
        bp[nt] = Z + (size_t)(jbase + nt * 16 + c16) * DIM + quad * 8;

    f32x4 acc[4][4];
    #pragma unroll
    for (int mt = 0; mt < 4; ++mt)
        #pragma unroll
        for (int nt = 0; nt < 4; ++nt)
            acc[mt][nt] = (f32x4){0.f, 0.f, 0.f, 0.f};

    // Register double-buffered K loop: load kk+1 while MFMAing kk.
    bf16x8 af[2][4], bfv[2][4];
    #pragma unroll
    for (int mt = 0; mt < 4; ++mt) af[0][mt] = *(const bf16x8*)(ap[mt]);
    #pragma unroll
    for (int nt = 0; nt < 4; ++nt) bfv[0][nt] = *(const bf16x8*)(bp[nt]);

    #pragma unroll
    for (int kk = 0; kk < 8; ++kk) {
        int cur = kk & 1, nxt = cur ^ 1;
        if (kk < 7) {
            #pragma unroll
            for (int mt = 0; mt < 4; ++mt)
                af[nxt][mt] = *(const bf16x8*)(ap[mt] + (kk + 1) * 32);
            #pragma unroll
            for (int nt = 0; nt < 4; ++nt)
                bfv[nxt][nt] = *(const bf16x8*)(bp[nt] + (kk + 1) * 32);
        }
        #pragma unroll
        for (int mt = 0; mt < 4; ++mt)
            #pragma unroll
            for (int nt = 0; nt < 4; ++nt)
                acc[mt][nt] = __builtin_amdgcn_mfma_f32_16x16x32_bf16(
                    af[cur][mt], bfv[cur][nt], acc[mt][nt], 0, 0, 0);
    }

    // Epilogue. Row of acc[mt][nt][rg] = rbase+mt*16+quad*4+rg,
    // col = jbase+nt*16+c16.
    float rsum[4][4];
    #pragma unroll
    for (int mt = 0; mt < 4; ++mt)
        #pragma unroll
        for (int rg = 0; rg < 4; ++rg) rsum[mt][rg] = 0.f;

    if (bx == by) {
        // Diagonal block: mask r==j, row-sums only.
        #pragma unroll
        for (int mt = 0; mt < 4; ++mt) {
            #pragma unroll
            for (int nt = 0; nt < 4; ++nt) {
                int j = jbase + nt * 16 + c16;
                #pragma unroll
                for (int rg = 0; rg < 4; ++rg) {
                    int r = rbase + mt * 16 + quad * 4 + rg;
                    float e = __expf(2.0f * acc[mt][nt][rg]);
                    rsum[mt][rg] += (r == j) ? 0.f : e;
                }
            }
        }
    } else {
        // Off-diagonal: no diagonal possible; row-sums AND col-sums.
        float csum[4] = {0.f, 0.f, 0.f, 0.f};
        #pragma unroll
        for (int mt = 0; mt < 4; ++mt) {
            #pragma unroll
            for (int nt = 0; nt < 4; ++nt) {
                #pragma unroll
                for (int rg = 0; rg < 4; ++rg) {
                    float e = __expf(2.0f * acc[mt][nt][rg]);
                    rsum[mt][rg] += e;
                    csum[nt] += e;
                }
            }
        }
        // col c16 of tile nt: partial covers this lane's 16 rows; sum the
        // 4 quads (lanes c16, c16+16, c16+32, c16+48) then atomic from quad 0.
        #pragma unroll
        for (int nt = 0; nt < 4; ++nt) {
            float v = csum[nt];
            v += __shfl_xor(v, 16, 64);
            v += __shfl_xor(v, 32, 64);
            if (quad == 0)
                atomicAdd(&den[jbase + nt * 16 + c16], v);
        }
    }

    // Row-sums: reduce the 16 col-lanes of each quad, atomic from c16==0.
    #pragma unroll
    for (int mt = 0; mt < 4; ++mt) {
        #pragma unroll
        for (int rg = 0; rg < 4; ++rg) {
            float v = rsum[mt][rg];
            v += __shfl_xor(v, 1, 64);
            v += __shfl_xor(v, 2, 64);
            v += __shfl_xor(v, 4, 64);
            v += __shfl_xor(v, 8, 64);
            if (c16 == 0)
                atomicAdd(&den[rbase + mt * 16 + quad * 4 + rg], v);
        }
    }
}

// ---------------------------------------------------------------------------
// K3: single block: out = (sum_r log(den[r]) - 4 * sum_p pos[p]) / 4096.
// ---------------------------------------------------------------------------
__global__ __launch_bounds__(256) void loss_kernel(
    const float* __restrict__ den, const float* __restrict__ pos,
    float* __restrict__ out)
{
    __shared__ float red[4];
    int t = threadIdx.x;
    float s = 0.f;
    for (int r = t; r < TWO_N; r += 256) s += logf(den[r]);
    for (int p = t; p < NB; p += 256) s -= 4.0f * pos[p];
    #pragma unroll
    for (int off = 32; off >= 1; off >>= 1) s += __shfl_xor(s, off, 64);
    int wave = t >> 6, lane = t & 63;
    if (lane == 0) red[wave] = s;
    __syncthreads();
    if (t == 0)
        out[0] = (red[0] + red[1] + red[2] + red[3]) * (1.0f / (float)TWO_N);
}

// ---------------------------------------------------------------------------
extern "C" void kernel_launch(void* const* d_in, const int* in_sizes, int n_in,
                              void* d_out, int out_size, void* d_ws, size_t ws_size,
                              hipStream_t stream)
{
    const float* emb_i = (const float*)d_in[0];
    const float* emb_j = (const float*)d_in[1];
    float* out = (float*)d_out;

    __hip_bfloat16* zb = (__hip_bfloat16*)d_ws;           // 4096*256 bf16 = 2 MB
    float* den = (float*)((char*)d_ws + (size_t)TWO_N * DIM * sizeof(__hip_bfloat16));
    float* pos = den + TWO_N;                             // 2048 f32

    nrm_kernel<<<NB / 4, 256, 0, stream>>>(emb_i, emb_j, zb, pos, den);

    dim3 g2(TWO_N / 128, TWO_N / 128);                    // 32 x 32, bx<=by live
    simexp_kernel<<<g2, 256, 0, stream>>>(zb, den);

    loss_kernel<<<1, 256, 0, stream>>>(den, pos, out);
}

// Round 4
// 94.399 us; speedup vs baseline: 6.0722x; 1.0757x over previous
//
#include <hip/hip_runtime.h>
#include <hip/hip_bf16.h>
#include <math.h>

// Problem constants (reference: BATCH=2048, D=256, TEMP=0.5)
#define NB      2048
#define TWO_N   4096
#define DIM     256
#define EPS     1e-12f

typedef __attribute__((ext_vector_type(8))) short  bf16x8;   // 8 bf16 = 4 VGPRs
typedef __attribute__((ext_vector_type(4))) float  f32x4;    // MFMA C/D

// ---------------------------------------------------------------------------
// K1: one wave per PAIR r in [0,2048): L2-normalize emb_i[r] -> z[r] and
// emb_j[r] -> z[r+NB] (bf16), and write the fp32-exact positive dot
// pos[r] = <z_i, z_j>. Also zeroes den[4096].
// ---------------------------------------------------------------------------
__global__ __launch_bounds__(256) void nrm_kernel(
    const float* __restrict__ emb_i, const float* __restrict__ emb_j,
    __hip_bfloat16* __restrict__ zb, float* __restrict__ pos,
    float* __restrict__ den)
{
    int t = threadIdx.x;
    int wave = t >> 6, lane = t & 63;
    int r = blockIdx.x * 4 + wave;              // pair index 0..2047
    float4 a = ((const float4*)(emb_i + (size_t)r * DIM))[lane];
    float4 b = ((const float4*)(emb_j + (size_t)r * DIM))[lane];
    float sa = a.x*a.x + a.y*a.y + a.z*a.z + a.w*a.w;
    float sb = b.x*b.x + b.y*b.y + b.z*b.z + b.w*b.w;
    float sd = a.x*b.x + a.y*b.y + a.z*b.z + a.w*b.w;
    #pragma unroll
    for (int off = 32; off >= 1; off >>= 1) {
        sa += __shfl_xor(sa, off, 64);
        sb += __shfl_xor(sb, off, 64);
        sd += __shfl_xor(sd, off, 64);
    }
    float si = 1.0f / fmaxf(sqrtf(sa), EPS);
    float sj = 1.0f / fmaxf(sqrtf(sb), EPS);

    union { __hip_bfloat16 h[4]; uint2 u; } pk;
    pk.h[0] = __float2bfloat16(a.x * si);
    pk.h[1] = __float2bfloat16(a.y * si);
    pk.h[2] = __float2bfloat16(a.z * si);
    pk.h[3] = __float2bfloat16(a.w * si);
    ((uint2*)(zb + (size_t)r * DIM))[lane] = pk.u;
    pk.h[0] = __float2bfloat16(b.x * sj);
    pk.h[1] = __float2bfloat16(b.y * sj);
    pk.h[2] = __float2bfloat16(b.z * sj);
    pk.h[3] = __float2bfloat16(b.w * sj);
    ((uint2*)(zb + (size_t)(r + NB) * DIM))[lane] = pk.u;

    if (lane == 0) pos[r] = sd * si * sj;
    if (t < 8) den[blockIdx.x * 8 + t] = 0.0f;  // 512 blocks x 8 = 4096
}

// ---------------------------------------------------------------------------
// K2: den[r] += sum_j exp(2 * z_r . z_j) via bf16 MFMA, symmetric: 1-D grid
// of exactly the 528 upper-triangle 128x128 tiles (id = by*(by+1)/2 + bx).
// Off-diagonal blocks scatter both row-sums and col-sums into den.
// 4 waves in 2x2; wave tile 64x64 = 4x4 MFMA 16x16x32 accumulators.
// K-loop register double-buffered, fragments straight from L2 (no LDS).
// launch_bounds(256,3): 3 blocks/CU for latency hiding (VGPR cap 170).
// Fragment layouts (verified m89/m91): A[m=lane&15][k=quad*8+j],
// B[k=quad*8+j][n=lane&15], C/D: col=lane&15, row=quad*4+reg.
// ---------------------------------------------------------------------------
__global__ __launch_bounds__(256, 3) void simexp_kernel(
    const __hip_bfloat16* __restrict__ zb, float* __restrict__ den)
{
    // Decode linear triangle index -> (bx, by), bx <= by.
    int id = blockIdx.x;
    int by = (int)((sqrtf(8.0f * (float)id + 1.0f) - 1.0f) * 0.5f);
    while ((by + 1) * (by + 2) / 2 <= id) ++by;   // fix float rounding
    while (by * (by + 1) / 2 > id) --by;
    int bx = id - by * (by + 1) / 2;

    const short* Z = (const short*)zb;
    int t = threadIdx.x;
    int w = t >> 6, lane = t & 63;
    int quad = lane >> 4, c16 = lane & 15;
    int wm = w >> 1, wn = w & 1;
    int rbase = bx * 128 + wm * 64;
    int jbase = by * 128 + wn * 64;

    const short* ap[4];
    const short* bp[4];
    #pragma unroll
    for (int mt = 0; mt < 4; ++mt)
        ap[mt] = Z + (size_t)(rbase + mt * 16 + c16) * DIM + quad * 8;
    #pragma unroll
    for (int nt = 0; nt < 4; ++nt)
        bp[nt] = Z + (size_t)(jbase + nt * 16 + c16) * DIM + quad * 8;

    f32x4 acc[4][4];
    #pragma unroll
    for (int mt = 0; mt < 4; ++mt)
        #pragma unroll
        for (int nt = 0; nt < 4; ++nt)
            acc[mt][nt] = (f32x4){0.f, 0.f, 0.f, 0.f};

    // Register double-buffered K loop: load kk+1 while MFMAing kk.
    bf16x8 af[2][4], bfv[2][4];
    #pragma unroll
    for (int mt = 0; mt < 4; ++mt) af[0][mt] = *(const bf16x8*)(ap[mt]);
    #pragma unroll
    for (int nt = 0; nt < 4; ++nt) bfv[0][nt] = *(const bf16x8*)(bp[nt]);

    #pragma unroll
    for (int kk = 0; kk < 8; ++kk) {
        int cur = kk & 1, nxt = cur ^ 1;
        if (kk < 7) {
            #pragma unroll
            for (int mt = 0; mt < 4; ++mt)
                af[nxt][mt] = *(const bf16x8*)(ap[mt] + (kk + 1) * 32);
            #pragma unroll
            for (int nt = 0; nt < 4; ++nt)
                bfv[nxt][nt] = *(const bf16x8*)(bp[nt] + (kk + 1) * 32);
        }
        #pragma unroll
        for (int mt = 0; mt < 4; ++mt)
            #pragma unroll
            for (int nt = 0; nt < 4; ++nt)
                acc[mt][nt] = __builtin_amdgcn_mfma_f32_16x16x32_bf16(
                    af[cur][mt], bfv[cur][nt], acc[mt][nt], 0, 0, 0);
    }

    // Epilogue. Row of acc[mt][nt][rg] = rbase+mt*16+quad*4+rg,
    // col = jbase+nt*16+c16.
    float rsum[4][4];
    #pragma unroll
    for (int mt = 0; mt < 4; ++mt)
        #pragma unroll
        for (int rg = 0; rg < 4; ++rg) rsum[mt][rg] = 0.f;

    if (bx == by) {
        // Diagonal block: mask r==j, row-sums only.
        #pragma unroll
        for (int mt = 0; mt < 4; ++mt) {
            #pragma unroll
            for (int nt = 0; nt < 4; ++nt) {
                int j = jbase + nt * 16 + c16;
                #pragma unroll
                for (int rg = 0; rg < 4; ++rg) {
                    int r = rbase + mt * 16 + quad * 4 + rg;
                    float e = __expf(2.0f * acc[mt][nt][rg]);
                    rsum[mt][rg] += (r == j) ? 0.f : e;
                }
            }
        }
    } else {
        // Off-diagonal: no diagonal possible; row-sums AND col-sums.
        float csum[4] = {0.f, 0.f, 0.f, 0.f};
        #pragma unroll
        for (int mt = 0; mt < 4; ++mt) {
            #pragma unroll
            for (int nt = 0; nt < 4; ++nt) {
                #pragma unroll
                for (int rg = 0; rg < 4; ++rg) {
                    float e = __expf(2.0f * acc[mt][nt][rg]);
                    rsum[mt][rg] += e;
                    csum[nt] += e;
                }
            }
        }
        // col c16 of tile nt: sum the 4 quads, atomic from quad 0.
        #pragma unroll
        for (int nt = 0; nt < 4; ++nt) {
            float v = csum[nt];
            v += __shfl_xor(v, 16, 64);
            v += __shfl_xor(v, 32, 64);
            if (quad == 0)
                atomicAdd(&den[jbase + nt * 16 + c16], v);
        }
    }

    // Row-sums: reduce the 16 col-lanes of each quad, atomic from c16==0.
    #pragma unroll
    for (int mt = 0; mt < 4; ++mt) {
        #pragma unroll
        for (int rg = 0; rg < 4; ++rg) {
            float v = rsum[mt][rg];
            v += __shfl_xor(v, 1, 64);
            v += __shfl_xor(v, 2, 64);
            v += __shfl_xor(v, 4, 64);
            v += __shfl_xor(v, 8, 64);
            if (c16 == 0)
                atomicAdd(&den[rbase + mt * 16 + quad * 4 + rg], v);
        }
    }
}

// ---------------------------------------------------------------------------
// K3: single block: out = (sum_r log(den[r]) - 4 * sum_p pos[p]) / 4096.
// ---------------------------------------------------------------------------
__global__ __launch_bounds__(256) void loss_kernel(
    const float* __restrict__ den, const float* __restrict__ pos,
    float* __restrict__ out)
{
    __shared__ float red[4];
    int t = threadIdx.x;
    float s = 0.f;
    for (int r = t; r < TWO_N; r += 256) s += logf(den[r]);
    for (int p = t; p < NB; p += 256) s -= 4.0f * pos[p];
    #pragma unroll
    for (int off = 32; off >= 1; off >>= 1) s += __shfl_xor(s, off, 64);
    int wave = t >> 6, lane = t & 63;
    if (lane == 0) red[wave] = s;
    __syncthreads();
    if (t == 0)
        out[0] = (red[0] + red[1] + red[2] + red[3]) * (1.0f / (float)TWO_N);
}

// ---------------------------------------------------------------------------
extern "C" void kernel_launch(void* const* d_in, const int* in_sizes, int n_in,
                              void* d_out, int out_size, void* d_ws, size_t ws_size,
                              hipStream_t stream)
{
    const float* emb_i = (const float*)d_in[0];
    const float* emb_j = (const float*)d_in[1];
    float* out = (float*)d_out;

    __hip_bfloat16* zb = (__hip_bfloat16*)d_ws;           // 4096*256 bf16 = 2 MB
    float* den = (float*)((char*)d_ws + (size_t)TWO_N * DIM * sizeof(__hip_bfloat16));
    float* pos = den + TWO_N;                             // 2048 f32

    nrm_kernel<<<NB / 4, 256, 0, stream>>>(emb_i, emb_j, zb, pos, den);

    int ntiles = TWO_N / 128;                             // 32
    simexp_kernel<<<ntiles * (ntiles + 1) / 2, 256, 0, stream>>>(zb, den);

    loss_kernel<<<1, 256, 0, stream>>>(den, pos, out);
}